// Round 13
// baseline (702.722 us; speedup 1.0000x reference)
//
#include <hip/hip_runtime.h>
#include <math.h>

#define B_    16
#define NP_   64
#define J_    17
#define C_    480
#define H_    128
#define W_    128
#define L_    4
#define HW_   (H_ * W_)
#define NSAMP (B_ * NP_)      // 1024
#define MROWS (NSAMP * J_)    // 17408
#define EPS_  1e-5f
#define NMAT  (1 + 2 * L_)    // 9 graph-conv weight matrices
#define NPAD  512             // weight N padded to 512 rows for maskless staging
#define TC    96              // transpose tile: channels
#define TS    64              // transpose tile: spatial
#define NT_   (256 * 5 * B_)  // 20480 transpose tiles
#define NW_   11520           // wsplit blocks

typedef __attribute__((ext_vector_type(8))) short bf16x8;
typedef __attribute__((ext_vector_type(4))) short bf16x4;
typedef __attribute__((ext_vector_type(16))) float f32x16;

__device__ __forceinline__ unsigned short f2bf(float f) {
    unsigned int u = __float_as_uint(f);
    unsigned int r = (u + 0x7fffu + ((u >> 16) & 1u)) >> 16;
    return (unsigned short)r;
}
__device__ __forceinline__ float bf2f(unsigned short h) {
    return __uint_as_float(((unsigned int)h) << 16);
}

// async global->LDS, 16B per lane; LDS dest = base + lane*16 (wave-uniform base)
#define GLD16(gsrc, ldst)                                                                 \
    __builtin_amdgcn_global_load_lds((const __attribute__((address_space(1))) void*)(gsrc), \
                                     (__attribute__((address_space(3))) void*)(ldst), 16, 0, 0)

// ---------------- merged prep: NCHW->NHWC bf16 transpose + weight split ----------------
__global__ __launch_bounds__(256) void k_prep(const float* __restrict__ feat,
                                              const float* __restrict__ Wh,
                                              const float* __restrict__ Wres,
                                              const float* __restrict__ Wp1,
                                              short* __restrict__ nhwc,
                                              short* __restrict__ WtH,
                                              short* __restrict__ WpH) {
    int bid = blockIdx.x;
    int tid = threadIdx.x;
    if (bid < NT_) {
        __shared__ float t[TC][73];   // stride 73 (mod 32 = 9): conflict-free
        int sb = bid & 255;
        int cb = (bid >> 8) % 5;
        int b  = bid / 1280;
        int c0 = cb * TC, s0 = sb * TS;
        const float* src = feat + ((size_t)b * C_ + c0) * HW_ + s0;
        #pragma unroll
        for (int i = 0; i < 6; ++i) {
            int f  = tid + i * 256;
            int c  = f >> 4;
            int sq = (f & 15) * 4;
            float4 v = *reinterpret_cast<const float4*>(src + (size_t)c * HW_ + sq);
            t[c][sq + 0] = v.x;
            t[c][sq + 1] = v.y;
            t[c][sq + 2] = v.z;
            t[c][sq + 3] = v.w;
        }
        __syncthreads();
        int sy = tid >> 2;
        int cx = (tid & 3) * (TC / 4);
        short* dst = nhwc + ((size_t)b * HW_ + s0 + sy) * C_ + c0 + cx;
        alignas(16) unsigned short tmp[TC / 4];
        #pragma unroll
        for (int i = 0; i < TC / 4; ++i) tmp[i] = f2bf(t[cx + i][sy]);
        #pragma unroll
        for (int i = 0; i < 3; ++i)
            *reinterpret_cast<uint4*>(dst + i * 8) = *reinterpret_cast<const uint4*>(tmp + i * 8);
    } else {
        int gid = (bid - NT_) * 256 + tid;
        const int t1 = NMAT * NPAD * C_;
        const int t2 = NPAD * 3 * C_;
        if (gid < t1) {
            int m   = gid / (NPAD * C_);
            int rem = gid % (NPAD * C_);
            int n = rem / C_;
            int k = rem % C_;
            float v = 0.f;
            if (n < C_) {
                const float* src = (m == 0) ? Wh : (Wres + (size_t)(m - 1) * C_ * C_);
                v = src[(size_t)k * C_ + n];
            }
            WtH[gid] = (short)f2bf(v);
        } else if (gid < t1 + t2) {
            int g2 = gid - t1;
            int n = g2 / (3 * C_);
            int k = g2 % (3 * C_);
            float v = (n < C_) ? Wp1[(size_t)n * 3 * C_ + k] : 0.f;
            WpH[g2] = (short)f2bf(v);
        }
    }
}

// ---------------- fused bilinear gather (NHWC bf16) + head adjacency mix -> bf16 A ----------------
__global__ __launch_bounds__(256) void k_gather_mix(const short* __restrict__ nhwc,
                                                    const float* __restrict__ coords,
                                                    const float* __restrict__ adj,
                                                    short* __restrict__ Ah) {
    __shared__ float sX[J_][C_];
    __shared__ float sadj[J_ * J_];
    __shared__ float sw[J_][4];
    __shared__ int   si[J_];
    int n = blockIdx.x;
    int b = n / NP_;
    for (int t = threadIdx.x; t < J_ * J_; t += 256) sadj[t] = adj[t];
    if (threadIdx.x < J_) {
        int j = threadIdx.x;
        int p = n * J_ + j;
        float x = coords[p * 2 + 0];
        float y = coords[p * 2 + 1];
        float x0f = fminf(fmaxf(floorf(x), 0.f), (float)(W_ - 2));
        float y0f = fminf(fmaxf(floorf(y), 0.f), (float)(H_ - 2));
        float wx = x - x0f, wy = y - y0f;
        sw[j][0] = (1.f - wx) * (1.f - wy);
        sw[j][1] = wx * (1.f - wy);
        sw[j][2] = (1.f - wx) * wy;
        sw[j][3] = wx * wy;
        si[j] = (int)y0f * W_ + (int)x0f;
    }
    __syncthreads();
    const short* base = nhwc + (size_t)b * HW_ * C_;
    for (int idx = threadIdx.x; idx < J_ * (C_ / 8); idx += 256) {
        int j  = idx / (C_ / 8);
        int c8 = (idx - j * (C_ / 8)) * 8;
        const short* p00 = base + (size_t)si[j] * C_ + c8;
        bf16x8 v00 = *reinterpret_cast<const bf16x8*>(p00);
        bf16x8 v01 = *reinterpret_cast<const bf16x8*>(p00 + C_);
        bf16x8 v10 = *reinterpret_cast<const bf16x8*>(p00 + W_ * C_);
        bf16x8 v11 = *reinterpret_cast<const bf16x8*>(p00 + W_ * C_ + C_);
        float w0 = sw[j][0], w1 = sw[j][1], w2 = sw[j][2], w3 = sw[j][3];
        #pragma unroll
        for (int e = 0; e < 8; ++e) {
            sX[j][c8 + e] = bf2f((unsigned short)v00[e]) * w0 +
                            bf2f((unsigned short)v01[e]) * w1 +
                            bf2f((unsigned short)v10[e]) * w2 +
                            bf2f((unsigned short)v11[e]) * w3;
        }
    }
    __syncthreads();
    size_t obase = (size_t)n * J_ * C_;
    for (int c = threadIdx.x; c < C_; c += 256) {
        float xv[J_];
        #pragma unroll
        for (int k = 0; k < J_; k++) xv[k] = sX[k][c];
        #pragma unroll
        for (int j = 0; j < J_; j++) {
            float s = 0.f;
            #pragma unroll
            for (int k = 0; k < J_; k++) s += sadj[j * J_ + k] * xv[k];
            Ah[obase + (size_t)j * C_ + c] = (short)f2bf(s);
        }
    }
}

// ---------------- adjacency mix on bf16 ----------------
__global__ __launch_bounds__(256) void k_mix_bf16(const short* __restrict__ Xin,
                                                  const float* __restrict__ adj,
                                                  short* __restrict__ Ah) {
    __shared__ float sadj[J_ * J_];
    for (int t = threadIdx.x; t < J_ * J_; t += 256) sadj[t] = adj[t];
    __syncthreads();
    int t = threadIdx.x;
    if (t >= 240) return;
    int n  = blockIdx.x * 2 + (t / 120);
    int c4 = (t % 120) * 4;
    const short* xb = Xin + (size_t)n * J_ * C_ + c4;
    float xf[J_][4];
    #pragma unroll
    for (int k = 0; k < J_; k++) {
        bf16x4 v = *reinterpret_cast<const bf16x4*>(xb + (size_t)k * C_);
        #pragma unroll
        for (int e = 0; e < 4; ++e) xf[k][e] = bf2f((unsigned short)v[e]);
    }
    short* yb = Ah + (size_t)n * J_ * C_ + c4;
    #pragma unroll
    for (int j = 0; j < J_; j++) {
        float a0 = 0.f, a1 = 0.f, a2 = 0.f, a3 = 0.f;
        #pragma unroll
        for (int k = 0; k < J_; k++) {
            float w = sadj[j * J_ + k];
            a0 = fmaf(w, xf[k][0], a0);
            a1 = fmaf(w, xf[k][1], a1);
            a2 = fmaf(w, xf[k][2], a2);
            a3 = fmaf(w, xf[k][3], a3);
        }
        bf16x4 o = {(short)f2bf(a0), (short)f2bf(a1), (short)f2bf(a2), (short)f2bf(a3)};
        *reinterpret_cast<bf16x4*>(yb + (size_t)j * C_) = o;
    }
}

// ---------------- bf16 MFMA GEMM v2: 32x32x16 shape, octet-major conflict-free LDS ----------------
// out[m,n](bf16) = relu(bn(sum_k A[m,k]B[k,n] + bias[n])) (+ res bf16)
// LDS tile per tensor: [oct 0..3][row 0..127][16B] (8 KB). Staging: wave wid stages octet wid,
// rows t*64+lane -> linear dest (no swizzle needed). Read: lanes 0-31 hit 32 consecutive 16B
// blocks -> conflict-free. Frag mapping: A row=lane&31, k=(lane>>5)*8 (+kf*16); C/D per m74/m101.
template <bool ADD>
__global__ __launch_bounds__(256) void k_gemm_mfma(const short* __restrict__ A,
                                                   const short* __restrict__ Bm,
                                                   const float* __restrict__ bias,
                                                   const float* __restrict__ bn4,
                                                   const short* res,   // may alias out
                                                   short* out,
                                                   int M, int N, int K) {
    __shared__ short lds[2 * 2 * 4096];   // [buf][A|B], 32 KB

    int nwg = gridDim.x * gridDim.y;
    int lin = blockIdx.y * gridDim.x + blockIdx.x;
    int cpx = nwg >> 3;
    int swz = (lin & 7) * cpx + (lin >> 3);
    const int row0 = (swz / gridDim.x) * 128;
    const int col0 = (swz % gridDim.x) * 128;

    const int tid  = threadIdx.x;
    const int lane = tid & 63;
    const int wid  = tid >> 6;
    const int wm0  = (wid >> 1) * 64;
    const int wn0  = (wid & 1) * 64;
    const int r31  = lane & 31;
    const int oct  = lane >> 5;          // 0/1

    f32x16 acc[2][2];
    #pragma unroll
    for (int i = 0; i < 2; i++)
        #pragma unroll
        for (int j = 0; j < 2; j++)
            #pragma unroll
            for (int e = 0; e < 16; e++) acc[i][j][e] = 0.f;

    // staging: wave wid stages k-octet wid; slice t covers rows t*64..t*64+63
    const short* pA0 = A  + (size_t)(row0 + lane) * K + wid * 8;
    const short* pA1 = A  + (size_t)(row0 + 64 + lane) * K + wid * 8;
    const short* pB0 = Bm + (size_t)(col0 + lane) * K + wid * 8;
    const short* pB1 = Bm + (size_t)(col0 + 64 + lane) * K + wid * 8;
    const int a0 = (2 * wid + 0) * 1024;   // byte offset in tensor region
    const int a1 = (2 * wid + 1) * 1024;

    const int NS = K / 32;
    {   // prologue: stage tile 0 into buf 0
        char* lb = (char*)lds;
        GLD16(pA0, lb + a0);        GLD16(pA1, lb + a1);
        GLD16(pB0, lb + 8192 + a0); GLD16(pB1, lb + 8192 + a1);
    }
    __syncthreads();

    for (int ks = 0; ks < NS; ++ks) {
        if (ks + 1 < NS) {
            const int kk = (ks + 1) * 32;
            char* lb = (char*)lds + ((ks + 1) & 1) * 16384;
            GLD16(pA0 + kk, lb + a0);        GLD16(pA1 + kk, lb + a1);
            GLD16(pB0 + kk, lb + 8192 + a0); GLD16(pB1 + kk, lb + 8192 + a1);
        }
        const short* lbc = lds + (ks & 1) * 8192;   // shorts
        bf16x8 fa[2][2], fb[2][2];
        #pragma unroll
        for (int mf = 0; mf < 2; ++mf)
            #pragma unroll
            for (int kf = 0; kf < 2; ++kf)
                fa[mf][kf] = *reinterpret_cast<const bf16x8*>(
                    lbc + (kf * 2 + oct) * 1024 + (wm0 + mf * 32 + r31) * 8);
        #pragma unroll
        for (int nf = 0; nf < 2; ++nf)
            #pragma unroll
            for (int kf = 0; kf < 2; ++kf)
                fb[nf][kf] = *reinterpret_cast<const bf16x8*>(
                    lbc + 4096 + (kf * 2 + oct) * 1024 + (wn0 + nf * 32 + r31) * 8);
        __builtin_amdgcn_s_setprio(1);
        #pragma unroll
        for (int mf = 0; mf < 2; ++mf)
            #pragma unroll
            for (int nf = 0; nf < 2; ++nf)
                #pragma unroll
                for (int kf = 0; kf < 2; ++kf)
                    acc[mf][nf] = __builtin_amdgcn_mfma_f32_32x32x16_bf16(
                        fa[mf][kf], fb[nf][kf], acc[mf][nf], 0, 0, 0);
        __builtin_amdgcn_s_setprio(0);
        __syncthreads();   // drains prefetch + guards buffer reuse
    }

    // ---- epilogue: C/D layout col=lane&31, row=(reg&3)+8*(reg>>2)+4*(lane>>5) ----
    #pragma unroll
    for (int nf = 0; nf < 2; ++nf) {
        int col = col0 + wn0 + nf * 32 + r31;
        if (col >= N) continue;
        float bia = bias[col];
        float g   = bn4[col];
        float be  = bn4[N + col];
        float mu  = bn4[2 * N + col];
        float va  = bn4[3 * N + col];
        float sc  = rsqrtf(va + EPS_) * g;
        #pragma unroll
        for (int mf = 0; mf < 2; ++mf) {
            int rbase = row0 + wm0 + mf * 32 + 4 * oct;
            #pragma unroll
            for (int reg = 0; reg < 16; ++reg) {
                int row = rbase + (reg & 3) + 8 * (reg >> 2);
                float v = acc[mf][nf][reg] + bia;
                v = (v - mu) * sc + be;
                v = fmaxf(v, 0.f);
                if (ADD) v += bf2f((unsigned short)res[(size_t)row * N + col]);
                out[(size_t)row * N + col] = (short)f2bf(v);
            }
        }
    }
}

// ---------------- pooling + concat (+center direct from NHWC) -> bf16 feats ----------------
__global__ __launch_bounds__(256) void k_pool(const short* __restrict__ Hb,
                                              const short* __restrict__ nhwc,
                                              const int* __restrict__ cidx,
                                              short* __restrict__ feats) {
    int n = blockIdx.x;
    int b = n / NP_;
    const short* cen = nhwc + ((size_t)b * HW_ + cidx[n]) * C_;
    for (int c = threadIdx.x; c < C_; c += 256) {
        float s = 0.f, m = -INFINITY;
        #pragma unroll
        for (int j = 0; j < J_; j++) {
            float v = bf2f((unsigned short)Hb[((size_t)n * J_ + j) * C_ + c]);
            s += v;
            m = fmaxf(m, v);
        }
        feats[(size_t)n * 3 * C_ + c]          = (short)f2bf(s * (1.f / (float)J_));
        feats[(size_t)n * 3 * C_ + C_ + c]     = (short)f2bf(m);
        feats[(size_t)n * 3 * C_ + 2 * C_ + c] = cen[c];
    }
}

// ---------------- final projection (P bf16) ----------------
__global__ __launch_bounds__(256) void k_final(const short* __restrict__ P,
                                               const float* __restrict__ W2,
                                               const float* __restrict__ b2,
                                               float* __restrict__ out) {
    int g = blockIdx.x * 256 + threadIdx.x;
    if (g >= NSAMP * 2 * J_) return;
    int m = g / (2 * J_);
    int o = g % (2 * J_);
    const short* pr = P + (size_t)m * C_;
    const float* wr = W2 + (size_t)o * C_;
    float s = 0.f;
    for (int k = 0; k < C_; k += 4) {
        s = fmaf(bf2f((unsigned short)pr[k + 0]), wr[k + 0], s);
        s = fmaf(bf2f((unsigned short)pr[k + 1]), wr[k + 1], s);
        s = fmaf(bf2f((unsigned short)pr[k + 2]), wr[k + 2], s);
        s = fmaf(bf2f((unsigned short)pr[k + 3]), wr[k + 3], s);
    }
    out[g] = s + b2[o];
}

extern "C" void kernel_launch(void* const* d_in, const int* in_sizes, int n_in,
                              void* d_out, int out_size, void* d_ws, size_t ws_size,
                              hipStream_t stream) {
    const float* features = (const float*)d_in[0];
    const float* coords   = (const float*)d_in[1];
    const int*   center   = (const int*)d_in[2];
    const float* adj      = (const float*)d_in[3];
    const float* Wh       = (const float*)d_in[4];
    const float* bh       = (const float*)d_in[5];
    const float* bn_head  = (const float*)d_in[6];
    const float* Wres     = (const float*)d_in[7];
    const float* bres     = (const float*)d_in[8];
    const float* bn_res   = (const float*)d_in[9];
    const float* Wp1      = (const float*)d_in[10];
    const float* bp1      = (const float*)d_in[11];
    const float* bn_pred  = (const float*)d_in[12];
    const float* Wp2      = (const float*)d_in[13];
    const float* bp2      = (const float*)d_in[14];
    float* out = (float*)d_out;

    // ---- workspace layout ----
    char* ws = (char*)d_ws;
    short* nhwc  = (short*)ws;   ws += (size_t)B_ * HW_ * C_ * 2;
    short* bufX  = (short*)ws;   ws += (size_t)MROWS * C_ * 2;
    short* bufH  = (short*)ws;   ws += (size_t)MROWS * C_ * 2;
    short* AhB   = (short*)ws;   ws += (size_t)MROWS * C_ * 2;
    short* featsB= (short*)ws;   ws += (size_t)NSAMP * 3 * C_ * 2;
    short* bufP  = (short*)ws;   ws += (size_t)NSAMP * C_ * 2;
    short* WtH   = (short*)ws;   ws += (size_t)NMAT * NPAD * C_ * 2;
    short* WpH   = (short*)ws;   ws += (size_t)NPAD * 3 * C_ * 2;

    dim3 gg(4, MROWS / 128);          // 544 blocks (544 % 8 == 0)
    dim3 gp(4, NSAMP / 128);          // 32 blocks  (32 % 8 == 0)

    k_prep<<<NT_ + NW_, 256, 0, stream>>>(features, Wh, Wres, Wp1, nhwc, WtH, WpH);

    k_gather_mix<<<NSAMP, 256, 0, stream>>>(nhwc, coords, adj, AhB);
    k_gemm_mfma<false><<<gg, 256, 0, stream>>>(AhB, WtH, bh, bn_head,
                                               nullptr, bufH, MROWS, C_, C_);

    for (int i = 0; i < L_; i++) {
        int m1 = 1 + 2 * i, m2 = 2 + 2 * i;
        k_mix_bf16<<<NSAMP / 2, 256, 0, stream>>>(bufH, adj, AhB);
        k_gemm_mfma<false><<<gg, 256, 0, stream>>>(
            AhB, WtH + (size_t)m1 * NPAD * C_,
            bres + (size_t)(2 * i) * C_, bn_res + (size_t)(2 * i) * 4 * C_,
            nullptr, bufX, MROWS, C_, C_);
        k_mix_bf16<<<NSAMP / 2, 256, 0, stream>>>(bufX, adj, AhB);
        k_gemm_mfma<true><<<gg, 256, 0, stream>>>(
            AhB, WtH + (size_t)m2 * NPAD * C_,
            bres + (size_t)(2 * i + 1) * C_, bn_res + (size_t)(2 * i + 1) * 4 * C_,
            bufH, bufH, MROWS, C_, C_);
    }

    k_pool<<<NSAMP, 256, 0, stream>>>(bufH, nhwc, center, featsB);

    k_gemm_mfma<false><<<gp, 256, 0, stream>>>(featsB, WpH, bp1, bn_pred,
                                               nullptr, bufP, NSAMP, C_, 3 * C_);

    k_final<<<(NSAMP * 2 * J_ + 255) / 256, 256, 0, stream>>>(bufP, Wp2, bp2, out);
}

// Round 14
// 574.202 us; speedup vs baseline: 1.2238x; 1.2238x over previous
//
#include <hip/hip_runtime.h>
#include <math.h>

#define B_    16
#define NP_   64
#define J_    17
#define C_    480
#define H_    128
#define W_    128
#define L_    4
#define HW_   (H_ * W_)
#define NSAMP (B_ * NP_)      // 1024
#define MROWS (NSAMP * J_)    // 17408
#define EPS_  1e-5f
#define NMAT  (1 + 2 * L_)    // 9 graph-conv weight matrices
#define NPAD  512             // weight N padded to 512 rows for maskless staging
#define TC    96              // transpose tile: channels
#define TS    64              // transpose tile: spatial
#define NT_   (256 * 5 * B_)  // 20480 transpose tiles
#define NW_   11520           // wsplit blocks

typedef __attribute__((ext_vector_type(8))) short bf16x8;
typedef __attribute__((ext_vector_type(4))) short bf16x4;
typedef __attribute__((ext_vector_type(4))) float f32x4;

__device__ __forceinline__ unsigned short f2bf(float f) {
    unsigned int u = __float_as_uint(f);
    unsigned int r = (u + 0x7fffu + ((u >> 16) & 1u)) >> 16;
    return (unsigned short)r;
}
__device__ __forceinline__ float bf2f(unsigned short h) {
    return __uint_as_float(((unsigned int)h) << 16);
}

// async global->LDS, 16B per lane; LDS dest = base + lane*16 (wave-uniform base)
#define GLD16(gsrc, ldst)                                                                 \
    __builtin_amdgcn_global_load_lds((const __attribute__((address_space(1))) void*)(gsrc), \
                                     (__attribute__((address_space(3))) void*)(ldst), 16, 0, 0)

// ---------------- merged prep: NCHW->NHWC bf16 transpose + weight split ----------------
__global__ __launch_bounds__(256) void k_prep(const float* __restrict__ feat,
                                              const float* __restrict__ Wh,
                                              const float* __restrict__ Wres,
                                              const float* __restrict__ Wp1,
                                              short* __restrict__ nhwc,
                                              short* __restrict__ WtH,
                                              short* __restrict__ WpH) {
    int bid = blockIdx.x;
    int tid = threadIdx.x;
    if (bid < NT_) {
        __shared__ float t[TC][73];   // stride 73 (mod 32 = 9): conflict-free
        int sb = bid & 255;
        int cb = (bid >> 8) % 5;
        int b  = bid / 1280;
        int c0 = cb * TC, s0 = sb * TS;
        const float* src = feat + ((size_t)b * C_ + c0) * HW_ + s0;
        #pragma unroll
        for (int i = 0; i < 6; ++i) {
            int f  = tid + i * 256;
            int c  = f >> 4;
            int sq = (f & 15) * 4;
            float4 v = *reinterpret_cast<const float4*>(src + (size_t)c * HW_ + sq);
            t[c][sq + 0] = v.x;
            t[c][sq + 1] = v.y;
            t[c][sq + 2] = v.z;
            t[c][sq + 3] = v.w;
        }
        __syncthreads();
        int sy = tid >> 2;
        int cx = (tid & 3) * (TC / 4);
        short* dst = nhwc + ((size_t)b * HW_ + s0 + sy) * C_ + c0 + cx;
        alignas(16) unsigned short tmp[TC / 4];
        #pragma unroll
        for (int i = 0; i < TC / 4; ++i) tmp[i] = f2bf(t[cx + i][sy]);
        #pragma unroll
        for (int i = 0; i < 3; ++i)
            *reinterpret_cast<uint4*>(dst + i * 8) = *reinterpret_cast<const uint4*>(tmp + i * 8);
    } else {
        int gid = (bid - NT_) * 256 + tid;
        const int t1 = NMAT * NPAD * C_;
        const int t2 = NPAD * 3 * C_;
        if (gid < t1) {
            int m   = gid / (NPAD * C_);
            int rem = gid % (NPAD * C_);
            int n = rem / C_;
            int k = rem % C_;
            float v = 0.f;
            if (n < C_) {
                const float* src = (m == 0) ? Wh : (Wres + (size_t)(m - 1) * C_ * C_);
                v = src[(size_t)k * C_ + n];
            }
            WtH[gid] = (short)f2bf(v);
        } else if (gid < t1 + t2) {
            int g2 = gid - t1;
            int n = g2 / (3 * C_);
            int k = g2 % (3 * C_);
            float v = (n < C_) ? Wp1[(size_t)n * 3 * C_ + k] : 0.f;
            WpH[g2] = (short)f2bf(v);
        }
    }
}

// ---------------- fused bilinear gather (NHWC bf16) + head adjacency mix -> bf16 A ----------------
__global__ __launch_bounds__(256) void k_gather_mix(const short* __restrict__ nhwc,
                                                    const float* __restrict__ coords,
                                                    const float* __restrict__ adj,
                                                    short* __restrict__ Ah) {
    __shared__ float sX[J_][C_];
    __shared__ float sadj[J_ * J_];
    __shared__ float sw[J_][4];
    __shared__ int   si[J_];
    int n = blockIdx.x;
    int b = n / NP_;
    for (int t = threadIdx.x; t < J_ * J_; t += 256) sadj[t] = adj[t];
    if (threadIdx.x < J_) {
        int j = threadIdx.x;
        int p = n * J_ + j;
        float x = coords[p * 2 + 0];
        float y = coords[p * 2 + 1];
        float x0f = fminf(fmaxf(floorf(x), 0.f), (float)(W_ - 2));
        float y0f = fminf(fmaxf(floorf(y), 0.f), (float)(H_ - 2));
        float wx = x - x0f, wy = y - y0f;
        sw[j][0] = (1.f - wx) * (1.f - wy);
        sw[j][1] = wx * (1.f - wy);
        sw[j][2] = (1.f - wx) * wy;
        sw[j][3] = wx * wy;
        si[j] = (int)y0f * W_ + (int)x0f;
    }
    __syncthreads();
    const short* base = nhwc + (size_t)b * HW_ * C_;
    for (int idx = threadIdx.x; idx < J_ * (C_ / 8); idx += 256) {
        int j  = idx / (C_ / 8);
        int c8 = (idx - j * (C_ / 8)) * 8;
        const short* p00 = base + (size_t)si[j] * C_ + c8;
        bf16x8 v00 = *reinterpret_cast<const bf16x8*>(p00);
        bf16x8 v01 = *reinterpret_cast<const bf16x8*>(p00 + C_);
        bf16x8 v10 = *reinterpret_cast<const bf16x8*>(p00 + W_ * C_);
        bf16x8 v11 = *reinterpret_cast<const bf16x8*>(p00 + W_ * C_ + C_);
        float w0 = sw[j][0], w1 = sw[j][1], w2 = sw[j][2], w3 = sw[j][3];
        #pragma unroll
        for (int e = 0; e < 8; ++e) {
            sX[j][c8 + e] = bf2f((unsigned short)v00[e]) * w0 +
                            bf2f((unsigned short)v01[e]) * w1 +
                            bf2f((unsigned short)v10[e]) * w2 +
                            bf2f((unsigned short)v11[e]) * w3;
        }
    }
    __syncthreads();
    size_t obase = (size_t)n * J_ * C_;
    for (int c = threadIdx.x; c < C_; c += 256) {
        float xv[J_];
        #pragma unroll
        for (int k = 0; k < J_; k++) xv[k] = sX[k][c];
        #pragma unroll
        for (int j = 0; j < J_; j++) {
            float s = 0.f;
            #pragma unroll
            for (int k = 0; k < J_; k++) s += sadj[j * J_ + k] * xv[k];
            Ah[obase + (size_t)j * C_ + c] = (short)f2bf(s);
        }
    }
}

// ---------------- adjacency mix on bf16 ----------------
__global__ __launch_bounds__(256) void k_mix_bf16(const short* __restrict__ Xin,
                                                  const float* __restrict__ adj,
                                                  short* __restrict__ Ah) {
    __shared__ float sadj[J_ * J_];
    for (int t = threadIdx.x; t < J_ * J_; t += 256) sadj[t] = adj[t];
    __syncthreads();
    int t = threadIdx.x;
    if (t >= 240) return;
    int n  = blockIdx.x * 2 + (t / 120);
    int c4 = (t % 120) * 4;
    const short* xb = Xin + (size_t)n * J_ * C_ + c4;
    float xf[J_][4];
    #pragma unroll
    for (int k = 0; k < J_; k++) {
        bf16x4 v = *reinterpret_cast<const bf16x4*>(xb + (size_t)k * C_);
        #pragma unroll
        for (int e = 0; e < 4; ++e) xf[k][e] = bf2f((unsigned short)v[e]);
    }
    short* yb = Ah + (size_t)n * J_ * C_ + c4;
    #pragma unroll
    for (int j = 0; j < J_; j++) {
        float a0 = 0.f, a1 = 0.f, a2 = 0.f, a3 = 0.f;
        #pragma unroll
        for (int k = 0; k < J_; k++) {
            float w = sadj[j * J_ + k];
            a0 = fmaf(w, xf[k][0], a0);
            a1 = fmaf(w, xf[k][1], a1);
            a2 = fmaf(w, xf[k][2], a2);
            a3 = fmaf(w, xf[k][3], a3);
        }
        bf16x4 o = {(short)f2bf(a0), (short)f2bf(a1), (short)f2bf(a2), (short)f2bf(a3)};
        *reinterpret_cast<bf16x4*>(yb + (size_t)j * C_) = o;
    }
}

// ---------------- 1-term bf16 MFMA GEMM (R12 core, BM=64): gload_lds + 2-phase + XCD swizzle ----------------
// out[m,n](bf16) = relu(bn(sum_k A[m,k]B[k,n] + bias[n])) (+ res bf16)
// Tile 64x128, 4 waves as 2(m)x2(n), each wave 32x64 out (2x4 16x16x32 frags, acc 32 VGPR).
// LDS per buffer: A 4KB (4 slices) + B 8KB (8 slices); wave w stages A slice w + B slices 2w,2w+1.
// Same XOR swizzle byte p=(r*64+cq*16)^((r&7)<<4), linear dest + inverse-swizzled source.
template <bool ADD>
__global__ __launch_bounds__(256) void k_gemm_mfma(const short* __restrict__ A,
                                                   const short* __restrict__ Bm,
                                                   const float* __restrict__ bias,
                                                   const float* __restrict__ bn4,
                                                   const short* res,   // may alias out
                                                   short* out,
                                                   int M, int N, int K) {
    __shared__ short lds[2 * 6144];   // [buf][A(2048) | B(4096)] shorts, 24 KB

    int nwg = gridDim.x * gridDim.y;
    int lin = blockIdx.y * gridDim.x + blockIdx.x;
    int cpx = nwg >> 3;
    int swz = (lin & 7) * cpx + (lin >> 3);
    const int row0 = (swz / gridDim.x) * 64;
    const int col0 = (swz % gridDim.x) * 128;

    const int tid  = threadIdx.x;
    const int lane = tid & 63;
    const int wid  = tid >> 6;
    const int wm0  = (wid >> 1) * 32;    // wave m-offset (0/32)
    const int wn0  = (wid & 1) * 64;     // wave n-offset (0/64)

    f32x4 acc[2][4];
    #pragma unroll
    for (int i = 0; i < 2; i++)
        #pragma unroll
        for (int j = 0; j < 4; j++) acc[i][j] = (f32x4){0.f, 0.f, 0.f, 0.f};

    const int kq = lane >> 4;
    const int fr = lane & 15;

    // per-lane inverse-swizzle source mapping: A slice wid; B slices 2*wid, 2*wid+1
    int rA, cqA, rB[2], cqB[2];
    {
        int p = wid * 1024 + lane * 16;
        int v = p >> 6;
        rA  = v ^ ((v >> 2) & 1);
        cqA = ((p >> 4) & 3) ^ (rA & 3);
    }
    #pragma unroll
    for (int t = 0; t < 2; ++t) {
        int p = (2 * wid + t) * 1024 + lane * 16;
        int v = p >> 6;
        int r = v ^ ((v >> 2) & 1);
        rB[t]  = r;
        cqB[t] = ((p >> 4) & 3) ^ (r & 3);
    }
    const short* pA  = A  + (size_t)(row0 + rA) * K + cqA * 8;
    const short* pB0 = Bm + (size_t)(col0 + rB[0]) * K + cqB[0] * 8;
    const short* pB1 = Bm + (size_t)(col0 + rB[1]) * K + cqB[1] * 8;
    const int aA  = wid * 1024;                 // byte offsets within buffer
    const int aB0 = 4096 + (2 * wid + 0) * 1024;
    const int aB1 = 4096 + (2 * wid + 1) * 1024;

    const int NS = K / 32;
    {   // prologue: stage tile 0 into buf 0
        char* lb = (char*)lds;
        GLD16(pA, lb + aA);
        GLD16(pB0, lb + aB0);
        GLD16(pB1, lb + aB1);
    }
    __syncthreads();

    for (int ks = 0; ks < NS; ++ks) {
        if (ks + 1 < NS) {            // prefetch next tile into other buffer
            const int kk = (ks + 1) * 32;
            char* lb = (char*)lds + ((ks + 1) & 1) * 12288;
            GLD16(pA + kk, lb + aA);
            GLD16(pB0 + kk, lb + aB0);
            GLD16(pB1 + kk, lb + aB1);
        }
        const short* lbc = lds + (ks & 1) * 6144;
        bf16x8 fa[2], fb[4];
        #pragma unroll
        for (int mf = 0; mf < 2; ++mf) {
            int r  = wm0 + mf * 16 + fr;
            int so = ((r * 64 + kq * 16) ^ ((r & 7) << 4)) >> 1;
            fa[mf] = *reinterpret_cast<const bf16x8*>(lbc + so);
        }
        #pragma unroll
        for (int nf = 0; nf < 4; ++nf) {
            int r  = wn0 + nf * 16 + fr;
            int so = ((r * 64 + kq * 16) ^ ((r & 7) << 4)) >> 1;
            fb[nf] = *reinterpret_cast<const bf16x8*>(lbc + 2048 + so);
        }
        __builtin_amdgcn_s_setprio(1);
        #pragma unroll
        for (int mf = 0; mf < 2; ++mf)
            #pragma unroll
            for (int nf = 0; nf < 4; ++nf)
                acc[mf][nf] = __builtin_amdgcn_mfma_f32_16x16x32_bf16(fa[mf], fb[nf], acc[mf][nf], 0, 0, 0);
        __builtin_amdgcn_s_setprio(0);
        __syncthreads();   // drains prefetch + guards buffer reuse
    }

    // ---- epilogue: C/D layout col=lane&15, row=(lane>>4)*4+reg ----
    const int rq = lane >> 4;
    #pragma unroll
    for (int nf = 0; nf < 4; ++nf) {
        int col = col0 + wn0 + nf * 16 + fr;
        if (col >= N) continue;
        float bia = bias[col];
        float g   = bn4[col];
        float be  = bn4[N + col];
        float mu  = bn4[2 * N + col];
        float va  = bn4[3 * N + col];
        float sc  = rsqrtf(va + EPS_) * g;
        #pragma unroll
        for (int mf = 0; mf < 2; ++mf) {
            #pragma unroll
            for (int r = 0; r < 4; ++r) {
                int row = row0 + wm0 + mf * 16 + rq * 4 + r;
                float v = acc[mf][nf][r] + bia;
                v = (v - mu) * sc + be;
                v = fmaxf(v, 0.f);
                if (ADD) v += bf2f((unsigned short)res[(size_t)row * N + col]);
                out[(size_t)row * N + col] = (short)f2bf(v);
            }
        }
    }
}

// ---------------- pooling + concat (+center direct from NHWC) -> bf16 feats ----------------
__global__ __launch_bounds__(256) void k_pool(const short* __restrict__ Hb,
                                              const short* __restrict__ nhwc,
                                              const int* __restrict__ cidx,
                                              short* __restrict__ feats) {
    int n = blockIdx.x;
    int b = n / NP_;
    const short* cen = nhwc + ((size_t)b * HW_ + cidx[n]) * C_;
    for (int c = threadIdx.x; c < C_; c += 256) {
        float s = 0.f, m = -INFINITY;
        #pragma unroll
        for (int j = 0; j < J_; j++) {
            float v = bf2f((unsigned short)Hb[((size_t)n * J_ + j) * C_ + c]);
            s += v;
            m = fmaxf(m, v);
        }
        feats[(size_t)n * 3 * C_ + c]          = (short)f2bf(s * (1.f / (float)J_));
        feats[(size_t)n * 3 * C_ + C_ + c]     = (short)f2bf(m);
        feats[(size_t)n * 3 * C_ + 2 * C_ + c] = cen[c];
    }
}

// ---------------- final projection (P bf16) ----------------
__global__ __launch_bounds__(256) void k_final(const short* __restrict__ P,
                                               const float* __restrict__ W2,
                                               const float* __restrict__ b2,
                                               float* __restrict__ out) {
    int g = blockIdx.x * 256 + threadIdx.x;
    if (g >= NSAMP * 2 * J_) return;
    int m = g / (2 * J_);
    int o = g % (2 * J_);
    const short* pr = P + (size_t)m * C_;
    const float* wr = W2 + (size_t)o * C_;
    float s = 0.f;
    for (int k = 0; k < C_; k += 4) {
        s = fmaf(bf2f((unsigned short)pr[k + 0]), wr[k + 0], s);
        s = fmaf(bf2f((unsigned short)pr[k + 1]), wr[k + 1], s);
        s = fmaf(bf2f((unsigned short)pr[k + 2]), wr[k + 2], s);
        s = fmaf(bf2f((unsigned short)pr[k + 3]), wr[k + 3], s);
    }
    out[g] = s + b2[o];
}

extern "C" void kernel_launch(void* const* d_in, const int* in_sizes, int n_in,
                              void* d_out, int out_size, void* d_ws, size_t ws_size,
                              hipStream_t stream) {
    const float* features = (const float*)d_in[0];
    const float* coords   = (const float*)d_in[1];
    const int*   center   = (const int*)d_in[2];
    const float* adj      = (const float*)d_in[3];
    const float* Wh       = (const float*)d_in[4];
    const float* bh       = (const float*)d_in[5];
    const float* bn_head  = (const float*)d_in[6];
    const float* Wres     = (const float*)d_in[7];
    const float* bres     = (const float*)d_in[8];
    const float* bn_res   = (const float*)d_in[9];
    const float* Wp1      = (const float*)d_in[10];
    const float* bp1      = (const float*)d_in[11];
    const float* bn_pred  = (const float*)d_in[12];
    const float* Wp2      = (const float*)d_in[13];
    const float* bp2      = (const float*)d_in[14];
    float* out = (float*)d_out;

    // ---- workspace layout ----
    char* ws = (char*)d_ws;
    short* nhwc  = (short*)ws;   ws += (size_t)B_ * HW_ * C_ * 2;
    short* bufX  = (short*)ws;   ws += (size_t)MROWS * C_ * 2;
    short* bufH  = (short*)ws;   ws += (size_t)MROWS * C_ * 2;
    short* AhB   = (short*)ws;   ws += (size_t)MROWS * C_ * 2;
    short* featsB= (short*)ws;   ws += (size_t)NSAMP * 3 * C_ * 2;
    short* bufP  = (short*)ws;   ws += (size_t)NSAMP * C_ * 2;
    short* WtH   = (short*)ws;   ws += (size_t)NMAT * NPAD * C_ * 2;
    short* WpH   = (short*)ws;   ws += (size_t)NPAD * 3 * C_ * 2;

    dim3 gg(4, MROWS / 64);           // 1088 blocks (1088 % 8 == 0)
    dim3 gp(4, NSAMP / 64);           // 64 blocks   (64 % 8 == 0)

    k_prep<<<NT_ + NW_, 256, 0, stream>>>(features, Wh, Wres, Wp1, nhwc, WtH, WpH);

    k_gather_mix<<<NSAMP, 256, 0, stream>>>(nhwc, coords, adj, AhB);
    k_gemm_mfma<false><<<gg, 256, 0, stream>>>(AhB, WtH, bh, bn_head,
                                               nullptr, bufH, MROWS, C_, C_);

    for (int i = 0; i < L_; i++) {
        int m1 = 1 + 2 * i, m2 = 2 + 2 * i;
        k_mix_bf16<<<NSAMP / 2, 256, 0, stream>>>(bufH, adj, AhB);
        k_gemm_mfma<false><<<gg, 256, 0, stream>>>(
            AhB, WtH + (size_t)m1 * NPAD * C_,
            bres + (size_t)(2 * i) * C_, bn_res + (size_t)(2 * i) * 4 * C_,
            nullptr, bufX, MROWS, C_, C_);
        k_mix_bf16<<<NSAMP / 2, 256, 0, stream>>>(bufX, adj, AhB);
        k_gemm_mfma<true><<<gg, 256, 0, stream>>>(
            AhB, WtH + (size_t)m2 * NPAD * C_,
            bres + (size_t)(2 * i + 1) * C_, bn_res + (size_t)(2 * i + 1) * 4 * C_,
            bufH, bufH, MROWS, C_, C_);
    }

    k_pool<<<NSAMP, 256, 0, stream>>>(bufH, nhwc, center, featsB);

    k_gemm_mfma<false><<<gp, 256, 0, stream>>>(featsB, WpH, bp1, bn_pred,
                                               nullptr, bufP, NSAMP, C_, 3 * C_);

    k_final<<<(NSAMP * 2 * J_ + 255) / 256, 256, 0, stream>>>(bufP, Wp2, bp2, out);
}